// Round 1
// 820.574 us; speedup vs baseline: 1.0243x; 1.0243x over previous
//
#include <hip/hip_runtime.h>
#include <hip/hip_bf16.h>
#include <math.h>

// ---------------------------------------------------------------------------
// InfNet: 2-layer GCN + Weibull epilogue.
// GEMMs: bf16x3 split as ONE pass: [Ah|Al|Ah] * [Bh;Bh;Bl] via K-wrap remap.
// Aggregations fp32 (kappa-path error amplification forbids bf16 gathers),
// restructured wave-per-node (barrier-free, no LDS): one 64-lane wave owns one
// node's CSR segment; row width matches wave (256 f32 = 64xfloat4 for agg1,
// 128 f32 = 64xfloat2 for agg2). kappa column dot fused into agg1 epilogue.
// ---------------------------------------------------------------------------

typedef unsigned short ushort_t;
typedef __attribute__((ext_vector_type(8))) short bf16x8;
typedef __attribute__((ext_vector_type(4))) float f32x4;

__device__ __forceinline__ ushort_t f2bf(float f) {
    union { float f; unsigned u; } x; x.f = f;
    unsigned r = x.u + 0x7FFF + ((x.u >> 16) & 1);   // RNE
    return (ushort_t)(r >> 16);
}
__device__ __forceinline__ float bf2f(ushort_t s) {
    union { unsigned u; float f; } x; x.u = ((unsigned)s) << 16; return x.f;
}

__device__ __forceinline__ void async_copy16(const void* gsrc, void* ldst) {
    __builtin_amdgcn_global_load_lds(
        (const __attribute__((address_space(1))) unsigned int*)gsrc,
        (__attribute__((address_space(3))) unsigned int*)ldst,
        16, 0, 0);
}

// ---------------- graph preprocessing ----------------

__global__ __launch_bounds__(256) void count_kernel(const int* __restrict__ dst,
                                                    int* __restrict__ cnt, int E)
{
    int e = blockIdx.x * blockDim.x + threadIdx.x;
    if (e < E) atomicAdd(&cnt[dst[e]], 1);
}

__global__ __launch_bounds__(1024) void scan_local(const int* __restrict__ cnt,
                                                   int* __restrict__ rowptr,
                                                   float* __restrict__ dinv,
                                                   int* __restrict__ blksum, int N)
{
    __shared__ int wsum[16];
    int tid = threadIdx.x, lane = tid & 63, wid = tid >> 6;
    int i = blockIdx.x * 1024 + tid;
    int v = (i < N) ? cnt[i] : 0;
    if (i < N) dinv[i] = rsqrtf((float)(v + 1));
    int s = v;
#pragma unroll
    for (int off = 1; off < 64; off <<= 1) {
        int t = __shfl_up(s, off, 64);
        if (lane >= off) s += t;
    }
    if (lane == 63) wsum[wid] = s;
    __syncthreads();
    if (tid < 16) {
        int w = wsum[tid];
#pragma unroll
        for (int off = 1; off < 16; off <<= 1) {
            int t = __shfl_up(w, off, 64);
            if (tid >= off) w += t;
        }
        wsum[tid] = w;
    }
    __syncthreads();
    int excl = s - v + (wid ? wsum[wid - 1] : 0);
    if (i < N) rowptr[i] = excl;
    if (tid == 0) blksum[blockIdx.x] = wsum[15];
}

__global__ __launch_bounds__(64) void scan_blk(const int* __restrict__ blksum,
                                               int* __restrict__ blkoff,
                                               int nblk, int* __restrict__ rowptr, int N)
{
    int tid = threadIdx.x;
    int v = (tid < nblk) ? blksum[tid] : 0;
    int s = v;
#pragma unroll
    for (int off = 1; off < 64; off <<= 1) {
        int t = __shfl_up(s, off, 64);
        if (tid >= off) s += t;
    }
    if (tid < nblk) blkoff[tid] = s - v;
    if (tid == nblk - 1) rowptr[N] = s;
}

__global__ __launch_bounds__(256) void scan_add(int* __restrict__ rowptr,
                                                int* __restrict__ cursor,
                                                const int* __restrict__ blkoff, int N)
{
    int i = blockIdx.x * blockDim.x + threadIdx.x;
    if (i < N) {
        int r = rowptr[i] + blkoff[i >> 10];
        rowptr[i] = r;
        cursor[i] = r;
    }
}

__global__ __launch_bounds__(256) void scatter_kernel(const int* __restrict__ src,
                                                      const int* __restrict__ dst,
                                                      int* __restrict__ cursor,
                                                      int* __restrict__ col, int E)
{
    int e = blockIdx.x * blockDim.x + threadIdx.x;
    if (e < E) {
        int d = dst[e];
        int pos = atomicAdd(&cursor[d], 1);
        col[pos] = src[e];
    }
}

// ---------------- operand conversion (bf16 hi/lo split) ----------------

__global__ __launch_bounds__(256) void conv_x(const float* __restrict__ x,
                                              ushort_t* __restrict__ Abig,
                                              int M, int M_pad)
{
    int id = blockIdx.x * blockDim.x + threadIdx.x;
    int r = id >> 7, q = id & 127;
    if (r >= M_pad) return;
    float4 v = make_float4(0.f, 0.f, 0.f, 0.f);
    if (r < M) v = *reinterpret_cast<const float4*>(&x[(size_t)r * 512 + q * 4]);
    ushort4 h, l;
    h.x = f2bf(v.x); l.x = f2bf(v.x - bf2f(h.x));
    h.y = f2bf(v.y); l.y = f2bf(v.y - bf2f(h.y));
    h.z = f2bf(v.z); l.z = f2bf(v.z - bf2f(h.z));
    h.w = f2bf(v.w); l.w = f2bf(v.w - bf2f(h.w));
    ushort_t* rowp = Abig + (size_t)r * 1024;
    *reinterpret_cast<ushort4*>(rowp + q * 4)       = h;
    *reinterpret_cast<ushort4*>(rowp + 512 + q * 4) = l;
}

// W0bigT (256 x 1536), row n: [hi(512) | hi(512) | lo(512)] of W0[:,n].
__global__ __launch_bounds__(256) void conv_w0(const float* __restrict__ W0,
                                               ushort_t* __restrict__ BT)
{
    int id = blockIdx.x * blockDim.x + threadIdx.x;
    int k = id & 511, n = id >> 9;
    if (n >= 256) return;
    float v = W0[(size_t)k * 256 + n];
    ushort_t h = f2bf(v);
    ushort_t l = f2bf(v - bf2f(h));
    ushort_t* rowp = BT + (size_t)n * 1536;
    rowp[k] = h; rowp[512 + k] = h; rowp[1024 + k] = l;
}

// W1bigT (128 x 768), row n: [hi(256) | hi(256) | lo(256)]; plus W1col fp32.
__global__ __launch_bounds__(256) void conv_w1(const float* __restrict__ W1,
                                               ushort_t* __restrict__ BT,
                                               float* __restrict__ W1col)
{
    int id = blockIdx.x * blockDim.x + threadIdx.x;
    int k = id & 255, n = id >> 8;
    if (n >= 128) return;
    float v = W1[(size_t)k * 129 + n];
    ushort_t h = f2bf(v);
    ushort_t l = f2bf(v - bf2f(h));
    ushort_t* rowp = BT + (size_t)n * 768;
    rowp[k] = h; rowp[256 + k] = h; rowp[512 + k] = l;
    if (n == 0) W1col[k] = W1[(size_t)k * 129 + 128];
}

// ---------------- MFMA GEMM: C = A(M x K eff) * BT(N x K)^T ----------------
// K iterates [0, K); A's k-index wraps at kwrap (so Ah reused for the Bl band).
// 128x128 tile, BK=32, 256 thr = 4 waves (2x2 of 64x64), 16x16x32 MFMA.
__global__ __launch_bounds__(256) void gemm_bf16(const ushort_t* __restrict__ A, int lda,
                                                 const ushort_t* __restrict__ BT, int ldbt,
                                                 float* __restrict__ C, int ldc,
                                                 int M, int K, int kwrap)
{
    __shared__ short As[128 * 32];
    __shared__ short Bs[128 * 32];

    int tid  = threadIdx.x;
    int w    = tid >> 6;
    int lane = tid & 63;
    int lm   = lane & 15;
    int lq   = lane >> 4;
    int bm   = blockIdx.x * 128;
    int bn   = blockIdx.y * 128;
    int wr   = (w >> 1) * 64;
    int wc   = (w & 1) * 64;

    f32x4 acc[4][4];
#pragma unroll
    for (int i = 0; i < 4; ++i)
#pragma unroll
        for (int j = 0; j < 4; ++j) acc[i][j] = (f32x4)(0.f);

    int srow = (lane >> 2);
    int scol = (lane & 3) * 16;

    for (int k0 = 0; k0 < K; k0 += 32) {
        int ka = (k0 < kwrap) ? k0 : (k0 - kwrap);   // A k-wrap (tiles never straddle)
#pragma unroll
        for (int q = 0; q < 2; ++q) {
            int r = w * 32 + q * 16 + srow;
            const char* ga = (const char*)A + ((size_t)(bm + r) * lda + ka) * 2 + scol;
            async_copy16(ga, (char*)As + (size_t)(w * 32 + q * 16) * 64);
        }
#pragma unroll
        for (int q = 0; q < 2; ++q) {
            int r = w * 32 + q * 16 + srow;
            const char* gb = (const char*)BT + ((size_t)(bn + r) * ldbt + k0) * 2 + scol;
            async_copy16(gb, (char*)Bs + (size_t)(w * 32 + q * 16) * 64);
        }
        __syncthreads();

        bf16x8 afr[4], bfr[4];
#pragma unroll
        for (int mi = 0; mi < 4; ++mi)
            afr[mi] = *reinterpret_cast<const bf16x8*>(&As[(wr + mi * 16 + lm) * 32 + lq * 8]);
#pragma unroll
        for (int ni = 0; ni < 4; ++ni)
            bfr[ni] = *reinterpret_cast<const bf16x8*>(&Bs[(wc + ni * 16 + lm) * 32 + lq * 8]);
#pragma unroll
        for (int mi = 0; mi < 4; ++mi)
#pragma unroll
            for (int ni = 0; ni < 4; ++ni)
                acc[mi][ni] = __builtin_amdgcn_mfma_f32_16x16x32_bf16(
                    afr[mi], bfr[ni], acc[mi][ni], 0, 0, 0);
        __syncthreads();
    }

#pragma unroll
    for (int mi = 0; mi < 4; ++mi) {
#pragma unroll
        for (int ni = 0; ni < 4; ++ni) {
            int rbase = bm + wr + mi * 16 + lq * 4;
            int cc    = bn + wc + ni * 16 + lm;
#pragma unroll
            for (int e = 0; e < 4; ++e) {
                int r = rbase + e;
                if (r < M) C[(size_t)r * ldc + cc] = acc[mi][ni][e];
            }
        }
    }
}

// ---------------- fused pieces ----------------

__device__ __forceinline__ float softplus_f(float x)
{
    return fmaxf(x, 0.f) + log1pf(expf(-fabsf(x)));
}

__device__ __forceinline__ void fma4(float4& a, float w, const float4& v)
{
    a.x = fmaf(w, v.x, a.x);
    a.y = fmaf(w, v.y, a.y);
    a.z = fmaf(w, v.z, a.z);
    a.w = fmaf(w, v.w, a.w);
}

__device__ __forceinline__ void fma2(float2& a, float w, const float2& v)
{
    a.x = fmaf(w, v.x, a.x);
    a.y = fmaf(w, v.y, a.y);
}

// layer-1 aggregation + softplus -> H1big bf16 [hi(256) | lo(256)] per node.
// Wave-per-node: row = 256 f32 = 64 lanes x float4. No LDS, no barriers; 4
// independent accumulators keep up to 12 loads in flight per wave. The kappa
// column dot (T2k = H1 . W1col) is fused into the epilogue (fp32, better than
// the old hi+lo reconstruction), eliminating the separate kappa_col pass.
__global__ __launch_bounds__(256) void agg1_kernel(const float* __restrict__ T1,
                                                   const float* __restrict__ dinv,
                                                   const int* __restrict__ rowptr,
                                                   const int* __restrict__ col,
                                                   const float* __restrict__ W1col,
                                                   ushort_t* __restrict__ H1big,
                                                   float* __restrict__ T2k, int N)
{
    int node = blockIdx.x * 4 + (threadIdx.x >> 6);
    if (node >= N) return;
    int lane = threadIdx.x & 63;
    float di = dinv[node];
    int beg = rowptr[node], end = rowptr[node + 1];

    float4 a0 = make_float4(0.f, 0.f, 0.f, 0.f);
    float4 a1 = a0, a2 = a0, a3 = a0;

    int e = beg;
    for (; e + 4 <= end; e += 4) {
        int s0 = col[e], s1 = col[e + 1], s2 = col[e + 2], s3 = col[e + 3];
        float w0 = dinv[s0], w1 = dinv[s1], w2 = dinv[s2], w3 = dinv[s3];
        float4 v0 = *reinterpret_cast<const float4*>(&T1[(size_t)s0 * 256 + lane * 4]);
        float4 v1 = *reinterpret_cast<const float4*>(&T1[(size_t)s1 * 256 + lane * 4]);
        float4 v2 = *reinterpret_cast<const float4*>(&T1[(size_t)s2 * 256 + lane * 4]);
        float4 v3 = *reinterpret_cast<const float4*>(&T1[(size_t)s3 * 256 + lane * 4]);
        fma4(a0, w0, v0); fma4(a1, w1, v1); fma4(a2, w2, v2); fma4(a3, w3, v3);
    }
    for (; e < end; ++e) {
        int s = col[e];
        float w = dinv[s];
        float4 v = *reinterpret_cast<const float4*>(&T1[(size_t)s * 256 + lane * 4]);
        fma4(a0, w, v);
    }

    float4 self = *reinterpret_cast<const float4*>(&T1[(size_t)node * 256 + lane * 4]);
    float4 o;
    o.x = softplus_f((a0.x + a1.x + a2.x + a3.x + self.x * di) * di);
    o.y = softplus_f((a0.y + a1.y + a2.y + a3.y + self.y * di) * di);
    o.z = softplus_f((a0.z + a1.z + a2.z + a3.z + self.z * di) * di);
    o.w = softplus_f((a0.w + a1.w + a2.w + a3.w + self.w * di) * di);

    ushort4 h, l;
    h.x = f2bf(o.x); l.x = f2bf(o.x - bf2f(h.x));
    h.y = f2bf(o.y); l.y = f2bf(o.y - bf2f(h.y));
    h.z = f2bf(o.z); l.z = f2bf(o.z - bf2f(h.z));
    h.w = f2bf(o.w); l.w = f2bf(o.w - bf2f(h.w));
    ushort_t* rowp = H1big + (size_t)node * 512;
    *reinterpret_cast<ushort4*>(rowp + lane * 4)       = h;
    *reinterpret_cast<ushort4*>(rowp + 256 + lane * 4) = l;

    // fused kappa column: T2k[node] = dot(H1[node,:], W1col)
    float4 wv = *reinterpret_cast<const float4*>(&W1col[lane * 4]);
    float tk = o.x * wv.x + o.y * wv.y + o.z * wv.z + o.w * wv.w;
#pragma unroll
    for (int off = 32; off > 0; off >>= 1)
        tk += __shfl_down(tk, off, 64);
    if (lane == 0) T2k[node] = tk;
}

// layer-2 aggregation + softplus + Weibull epilogue. Wave-per-node: row =
// 128 f32 = 64 lanes x float2. kappa-path accumulated redundantly across
// lanes (broadcast loads), so no cross-lane reduction is needed at all.
__global__ __launch_bounds__(256) void agg2_kernel(const float* __restrict__ T2,
                                                   const float* __restrict__ T2k,
                                                   const float* __restrict__ dinv,
                                                   const int* __restrict__ rowptr,
                                                   const int* __restrict__ col,
                                                   float* __restrict__ z_out,
                                                   float* __restrict__ lbd_out,
                                                   float* __restrict__ kap_out, int N)
{
    int node = blockIdx.x * 4 + (threadIdx.x >> 6);
    if (node >= N) return;
    int lane = threadIdx.x & 63;
    float di = dinv[node];
    int beg = rowptr[node], end = rowptr[node + 1];

    float2 a0 = make_float2(0.f, 0.f);
    float2 a1 = a0, a2 = a0, a3 = a0;
    float k0 = 0.f, k1 = 0.f, k2 = 0.f, k3 = 0.f;

    int e = beg;
    for (; e + 4 <= end; e += 4) {
        int s0 = col[e], s1 = col[e + 1], s2 = col[e + 2], s3 = col[e + 3];
        float w0 = dinv[s0], w1 = dinv[s1], w2 = dinv[s2], w3 = dinv[s3];
        k0 = fmaf(w0, T2k[s0], k0);
        k1 = fmaf(w1, T2k[s1], k1);
        k2 = fmaf(w2, T2k[s2], k2);
        k3 = fmaf(w3, T2k[s3], k3);
        float2 v0 = *reinterpret_cast<const float2*>(&T2[(size_t)s0 * 128 + lane * 2]);
        float2 v1 = *reinterpret_cast<const float2*>(&T2[(size_t)s1 * 128 + lane * 2]);
        float2 v2 = *reinterpret_cast<const float2*>(&T2[(size_t)s2 * 128 + lane * 2]);
        float2 v3 = *reinterpret_cast<const float2*>(&T2[(size_t)s3 * 128 + lane * 2]);
        fma2(a0, w0, v0); fma2(a1, w1, v1); fma2(a2, w2, v2); fma2(a3, w3, v3);
    }
    for (; e < end; ++e) {
        int s = col[e];
        float w = dinv[s];
        k0 = fmaf(w, T2k[s], k0);
        float2 v = *reinterpret_cast<const float2*>(&T2[(size_t)s * 128 + lane * 2]);
        fma2(a0, w, v);
    }

    float2 self = *reinterpret_cast<const float2*>(&T2[(size_t)node * 128 + lane * 2]);
    float2 sp;
    sp.x = softplus_f((a0.x + a1.x + a2.x + a3.x + self.x * di) * di);
    sp.y = softplus_f((a0.y + a1.y + a2.y + a3.y + self.y * di) * di);

    float ak = ((k0 + k1 + k2 + k3) + T2k[node] * di) * di;
    float kv = softplus_f(ak) + 0.1f;
    float g  = expf(lgammaf(1.0f + 1.0f / kv));
    if (lane == 0) kap_out[node] = kv;

    size_t o = (size_t)node * 128 + lane * 2;
    float2 zv = make_float2(sp.x * g, sp.y * g);
    *reinterpret_cast<float2*>(&lbd_out[o]) = sp;
    *reinterpret_cast<float2*>(&z_out[o])   = zv;
}

extern "C" void kernel_launch(void* const* d_in, const int* in_sizes, int n_in,
                              void* d_out, int out_size, void* d_ws, size_t ws_size,
                              hipStream_t stream)
{
    const float* x  = (const float*)d_in[0];
    const int*   ei = (const int*)d_in[1];
    const float* W0 = (const float*)d_in[2];
    const float* W1 = (const float*)d_in[3];

    const int N = in_sizes[0] / 512;      // 50000
    const int E = in_sizes[1] / 2;        // 1600000
    const int* src = ei;
    const int* dst = ei + E;

    const int mblocks = (N + 127) / 128;   // 391
    const int M_pad   = mblocks * 128;     // 50048
    const int nchunk  = (N + 1023) / 1024; // 49

    char* w = (char*)d_ws;
    size_t off = 0;
    auto take = [&](size_t bytes) -> void* {
        void* p = (void*)(w + off);
        off = (off + bytes + 255) & ~(size_t)255;
        return p;
    };
    int*      cnt    = (int*)take((size_t)N * 4);
    int*      rowptr = (int*)take((size_t)(N + 1) * 4);
    int*      cursor = (int*)take((size_t)N * 4);
    float*    dinv   = (float*)take((size_t)N * 4);
    int*      col    = (int*)take((size_t)E * 4);
    int*      blksum = (int*)take(64 * 4);
    int*      blkoff = (int*)take(64 * 4);
    ushort_t* W0bigT = (ushort_t*)take((size_t)256 * 1536 * 2);
    ushort_t* W1bigT = (ushort_t*)take((size_t)128 * 768 * 2);
    float*    W1col  = (float*)take((size_t)256 * 4);
    float*    T2k    = (float*)take((size_t)N * 4);
    float*    T1     = (float*)take((size_t)N * 256 * 4);
    float*    T2     = T1;                 // T1 dead after agg1; reuse
    ushort_t* Abig   = (ushort_t*)take((size_t)M_pad * 1024 * 2);   // 102.5 MB
    ushort_t* H1big  = Abig;               // alias: Abig dead after gemm1

    float* z_out   = (float*)d_out;
    float* lbd_out = z_out + (size_t)N * 128;
    float* kap_out = lbd_out + (size_t)N * 128;

    hipMemsetAsync(cnt, 0, (size_t)N * 4, stream);
    count_kernel<<<(E + 255) / 256, 256, 0, stream>>>(dst, cnt, E);
    scan_local<<<nchunk, 1024, 0, stream>>>(cnt, rowptr, dinv, blksum, N);
    scan_blk<<<1, 64, 0, stream>>>(blksum, blkoff, nchunk, rowptr, N);
    scan_add<<<(N + 255) / 256, 256, 0, stream>>>(rowptr, cursor, blkoff, N);
    scatter_kernel<<<(E + 255) / 256, 256, 0, stream>>>(src, dst, cursor, col, E);

    conv_x<<<(M_pad * 128) / 256, 256, 0, stream>>>(x, Abig, N, M_pad);
    conv_w0<<<(256 * 512) / 256, 256, 0, stream>>>(W0, W0bigT);
    conv_w1<<<(128 * 256) / 256, 256, 0, stream>>>(W1, W1bigT, W1col);

    // GEMM1: T1 = x @ W0, full bf16x3 split in one pass (K=1536, A wraps at 1024).
    dim3 g1(mblocks, 2);
    gemm_bf16<<<g1, 256, 0, stream>>>(Abig, 1024, W0bigT, 1536, T1, 256, N, 1536, 1024);

    // agg1: wave-per-node (4 nodes per 256-thr block), fused kappa column.
    agg1_kernel<<<(N + 3) / 4, 256, 0, stream>>>(T1, dinv, rowptr, col, W1col, H1big, T2k, N);

    // GEMM2: T2 = H1 @ W1main, one pass (K=768, A wraps at 512).
    dim3 g2(mblocks, 1);
    gemm_bf16<<<g2, 256, 0, stream>>>(H1big, 512, W1bigT, 768, T2, 128, N, 768, 512);

    agg2_kernel<<<(N + 3) / 4, 256, 0, stream>>>(T2, T2k, dinv, rowptr, col,
                                                 z_out, lbd_out, kap_out, N);
}